// Round 7
// baseline (782.974 us; speedup 1.0000x reference)
//
#include <hip/hip_runtime.h>
#include <cmath>
#include <cstdint>
#include <cstddef>

typedef unsigned short bf16_t;
typedef __attribute__((ext_vector_type(8))) short short8;
typedef __attribute__((ext_vector_type(4))) float floatx4;
typedef __attribute__((ext_vector_type(2))) _Float16 half2_t;

__device__ __forceinline__ float bf2f(bf16_t b){
  unsigned int u = ((unsigned int)b) << 16;
  return __uint_as_float(u);
}
__device__ __forceinline__ bf16_t f2bf(float f){
  unsigned int u = __float_as_uint(f);
  unsigned int r = (u + 0x7fffu + ((u >> 16) & 1u)) >> 16;  // RNE
  return (bf16_t)r;
}
__device__ __forceinline__ unsigned int f2bf2(float a, float b){
  return (unsigned int)f2bf(a) | ((unsigned int)f2bf(b) << 16);
}
__device__ __forceinline__ float sigf(float x){ return 1.0f / (1.0f + expf(-x)); }

__device__ __forceinline__ float dot2(half2_t a, half2_t b, float c){
#if __has_builtin(__builtin_amdgcn_fdot2)
  return __builtin_amdgcn_fdot2(a, b, c, false);
#else
  return c + (float)a.x * (float)b.x + (float)a.y * (float)b.y;
#endif
}

__device__ __forceinline__ void gload_lds16(const bf16_t* g, bf16_t* lds){
  __builtin_amdgcn_global_load_lds(
      (const __attribute__((address_space(1))) unsigned int*)g,
      (__attribute__((address_space(3))) unsigned int*)lds, 16, 0, 0);
}

// ---------------- mega prep kernel: adds, whh pack, LUTs, stat zero, A2mat K-pad ----------------
__global__ void prep_misc(const float* __restrict__ a1, const float* __restrict__ r1, float* __restrict__ o1,
                          const float* __restrict__ a2, const float* __restrict__ r2, float* __restrict__ o2,
                          const float* __restrict__ bi1, const float* __restrict__ bh1, float* __restrict__ ob1,
                          const float* __restrict__ bi2, const float* __restrict__ bh2, float* __restrict__ ob2,
                          const float* __restrict__ Whh1, half2_t* __restrict__ Wp1,
                          const float* __restrict__ Whh2, half2_t* __restrict__ Wp2,
                          unsigned short* __restrict__ lut1, unsigned short* __restrict__ lut2,
                          float* __restrict__ stats, bf16_t* __restrict__ A2mat){
  int i = blockIdx.x * blockDim.x + threadIdx.x;
  if (i < 8125){ o1[i] = a1[i] + r1[i]; o2[i] = a2[i] + r2[i]; }
  if (i < 384) ob1[i] = bi1[i] + bh1[i];
  if (i < 768) ob2[i] = bi2[i] + bh2[i];
  if (i < 736) stats[i] = 0.f;
  if (i < 18432){                       // pack Whh1 (H=96): Wp[j2*384+t]
    int t = i % 384, j2 = i / 384;
    half2_t w; w.x = (_Float16)Whh1[(size_t)t * 96 + 2 * j2];
    w.y = (_Float16)Whh1[(size_t)t * 96 + 2 * j2 + 1];
    Wp1[i] = w;
  }
  if (i < 73728){                       // pack Whh2 (H=192)
    int t = i % 768, j2 = i / 768;
    half2_t w; w.x = (_Float16)Whh2[(size_t)t * 192 + 2 * j2];
    w.y = (_Float16)Whh2[(size_t)t * 192 + 2 * j2 + 1];
    Wp2[i] = w;
  }
  // levy pair LUTs: flat p -> (i<<8)|j
  if (i < 4560){
    int d = 96, p = i;
    int r = (int)(((2.0 * d - 1.0) - sqrt((2.0 * d - 1.0) * (2.0 * d - 1.0) - 8.0 * (double)p)) * 0.5);
    if (r < 0) r = 0;
    while (r + 1 <= d - 2 && (r + 1) * (d - 1) - ((r + 1) * r) / 2 <= p) ++r;
    while (r > 0 && r * (d - 1) - (r * (r - 1)) / 2 > p) --r;
    int jj = p - (r * (d - 1) - (r * (r - 1)) / 2);
    lut1[p] = (unsigned short)((r << 8) | (r + 1 + jj));
  }
  if (i < 18336){
    int d = 192, p = i;
    int r = (int)(((2.0 * d - 1.0) - sqrt((2.0 * d - 1.0) * (2.0 * d - 1.0) - 8.0 * (double)p)) * 0.5);
    if (r < 0) r = 0;
    while (r + 1 <= d - 2 && (r + 1) * (d - 1) - ((r + 1) * r) / 2 <= p) ++r;
    while (r > 0 && r * (d - 1) - (r * (r - 1)) / 2 > p) --r;
    int jj = p - (r * (d - 1) - (r * (r - 1)) / 2);
    lut2[p] = (unsigned short)((r << 8) | (r + 1 + jj));
  }
  if (i < 160000){                      // A2mat K-pad cols [1248,1280), 5000 rows
    int row = i >> 5, col = 1248 + (i & 31);
    A2mat[(size_t)row * 1280 + col] = 0;
  }
}

// ---------------- data batchnorm: x(N,C,T,V,M) -> h1[(nm*C+c)*T+t][V] ----------------
__global__ void data_bn_kernel(const float* __restrict__ x, const float* __restrict__ g,
                               const float* __restrict__ bb, float* __restrict__ h1,
                               int N, int C, int T, int V, int M){
  int ch = blockIdx.x;             // (m*V + v)*C + c
  int m = ch / (V * C);
  int v = (ch / C) % V;
  int c = ch % C;
  int tid = threadIdx.x;
  int cnt = N * T;
  float s = 0.f, s2 = 0.f;
  for (int i = tid; i < cnt; i += 64){
    int n = i / T, t = i % T;
    float val = x[(((size_t)(n * C + c) * T + t) * V + v) * M + m];
    s += val; s2 += val * val;
  }
  for (int off = 32; off; off >>= 1){ s += __shfl_down(s, off); s2 += __shfl_down(s2, off); }
  s = __shfl(s, 0); s2 = __shfl(s2, 0);
  float mean = s / cnt;
  float rstd = rsqrtf(s2 / cnt - mean * mean + 1e-5f);
  float gg = g[ch], bo = bb[ch];
  for (int i = tid; i < cnt; i += 64){
    int n = i / T, t = i % T;
    float val = x[(((size_t)(n * C + c) * T + t) * V + v) * M + m];
    float y = (val - mean) * rstd * gg + bo;
    h1[((size_t)((n * M + m) * C + c) * T + t) * V + v] = y;
  }
}

// ---------------- GCN1 fused: support + W-contract + colstats. block = (nm,t) ----------------
__global__ __launch_bounds__(256)
void gcn1_fused(const float* __restrict__ A, const float* __restrict__ h1,
                const float* __restrict__ W1, const float* __restrict__ b1,
                float* __restrict__ y1, float* __restrict__ ssum, float* __restrict__ ssq, int T){
  __shared__ float h[3][25];
  __shared__ float sup[3][325];
  __shared__ float lsum[96], lsq[96];
  int blk = blockIdx.x;
  int nm = blk / T, t = blk % T;
  int tid = threadIdx.x;
  if (tid < 75){
    int c = tid / 25, v = tid % 25;
    h[c][v] = h1[((size_t)(nm * 3 + c) * T + t) * 25 + v];
  }
  if (tid < 96){ lsum[tid] = 0.f; lsq[tid] = 0.f; }
  __syncthreads();
  for (int w = tid; w < 975; w += 256){
    int c = w / 325, ww = w % 325;
    const float* ar = A + ww * 25;
    float acc = 0.f;
    #pragma unroll
    for (int u = 0; u < 25; ++u) acc += ar[u] * h[c][u];
    sup[c][ww] = acc;
  }
  __syncthreads();
  for (int o2 = tid; o2 < 2400; o2 += 256){
    int v = o2 / 96, o = o2 % 96;
    float acc = b1[o];
    #pragma unroll
    for (int k = 0; k < 13; ++k)
      #pragma unroll
      for (int c = 0; c < 3; ++c)
        acc += W1[o * 39 + k * 3 + c] * sup[c][k * 25 + v];
    y1[((size_t)blk * 25 + v) * 96 + o] = acc;
    atomicAdd(&lsum[o], acc);
    atomicAdd(&lsq[o], acc * acc);
  }
  __syncthreads();
  if (tid < 96){ atomicAdd(&ssum[tid], lsum[tid]); atomicAdd(&ssq[tid], lsq[tid]); }
}

// ---------------- feats with inline BN+relu: reads y-mat + stats, writes bf16 rows ----------------
struct SegTable { int st[50]; int en[50]; };

__global__ void feats_bn_kernel(const float* __restrict__ ymat, const float* __restrict__ sum,
                                const float* __restrict__ sumsq, const float* __restrict__ g,
                                const float* __restrict__ bb, bf16_t* __restrict__ feats,
                                SegTable segs, const unsigned int* __restrict__ lut32,
                                int T, int d, int S, int L, int pairs, int rowlenP, int R){
  __shared__ float pts[4][192];
  int bs = blockIdx.x;
  int b = bs / S, s = bs % S;
  int nm = b / 25, v = b % 25;
  int st = segs.st[s], en = segs.en[s];
  int nt = blockDim.x, tid = threadIdx.x;
  for (int l = 0; l < L; ++l){
    int t = st + l; if (t > en) t = en;
    const float* yrow = ymat + ((size_t)(nm * T + t) * 25 + v) * d;
    for (int i = tid; i < d; i += nt){
      float mean = sum[i] / R;
      float rstd = rsqrtf(sumsq[i] / R - mean * mean + 1e-5f);
      pts[l][i] = fmaxf((yrow[i] - mean) * rstd * g[i] + bb[i], 0.f);
    }
  }
  __syncthreads();
  unsigned int* frow32 = reinterpret_cast<unsigned int*>(feats + (size_t)bs * rowlenP);
  int d2 = d >> 1;
  for (int i2 = tid; i2 < d2; i2 += nt){
    int i = 2 * i2;
    frow32[i2]      = f2bf2(pts[0][i], pts[0][i + 1]);
    frow32[d2 + i2] = f2bf2(pts[L - 1][i] - pts[0][i], pts[L - 1][i + 1] - pts[0][i + 1]);
  }
  int rowlen2 = (2 * d + pairs) >> 1, rowlenP2 = rowlenP >> 1;
  for (int i = tid + rowlen2; i < rowlenP2; i += nt) frow32[i] = 0;  // K pad
  int Lm2 = L - 2;
  unsigned int* lrow32 = frow32 + d;
  int pairs2 = pairs >> 1;
  for (int p2 = tid; p2 < pairs2; p2 += nt){
    unsigned int ee = lut32[p2];
    int i0 = (ee >> 8) & 255, j0 = ee & 255;
    int i1 = ee >> 24, j1 = (ee >> 16) & 255;
    float acc0 = 0.f, acc1 = 0.f;
    for (int l = 1; l <= Lm2; ++l){
      float ri = pts[l][i0] - pts[0][i0], rj = pts[l][j0] - pts[0][j0];
      float di = pts[l + 1][i0] - pts[l][i0], dj = pts[l + 1][j0] - pts[l][j0];
      acc0 += ri * dj - rj * di;
      float ri1 = pts[l][i1] - pts[0][i1], rj1 = pts[l][j1] - pts[0][j1];
      float di1 = pts[l + 1][i1] - pts[l][i1], dj1 = pts[l + 1][j1] - pts[l][j1];
      acc1 += ri1 * dj1 - rj1 * di1;
    }
    lrow32[p2] = f2bf2(0.5f * acc0, 0.5f * acc1);
  }
}

// ---------------- split-K MFMA NT GEMM, BK=64, XOR swizzle; A bf16 (global_load_lds),
// ---------------- B fp32 converted in-register during staging. Kb = valid B cols (Kb%8==0).
__global__ __launch_bounds__(256)
void gemm_mfma_f32b(const bf16_t* __restrict__ A, const float* __restrict__ B,
                    float* __restrict__ P, int M, int N, int K, int Kb){
  __shared__ bf16_t As[128 * 64];
  __shared__ bf16_t Bs[128 * 64];
  const int tid = threadIdx.x;
  const int lane = tid & 63, wv = tid >> 6;
  const int bm = blockIdx.x * 128, bn = blockIdx.y * 128;
  const int wr = (wv >> 1) * 64, wc = (wv & 1) * 64;
  const int m_l = lane & 15, q = lane >> 4;

  const int ksteps = K >> 6;
  const int Z = gridDim.z, z = blockIdx.z;
  const int per = (ksteps + Z - 1) / Z;
  const int ks0 = z * per;
  const int ks1 = (ks0 + per < ksteps) ? ks0 + per : ksteps;

  const int rlane = lane >> 3;
  const int slane = lane & 7;
  const int colc = (slane ^ rlane) * 8;
  const bf16_t* gA[4];
  const float* gBf[4];
  bf16_t* lA[4];
  bf16_t* lB[4];
  #pragma unroll
  for (int it = 0; it < 4; ++it){
    int c = it * 4 + wv;
    int rowA = bm + c * 8 + rlane; if (rowA > M - 1) rowA = M - 1;
    int rowB = bn + c * 8 + rlane; if (rowB > N - 1) rowB = N - 1;
    gA[it] = A + (size_t)rowA * K + colc;
    gBf[it] = B + (size_t)rowB * Kb;
    lA[it] = &As[c * 512];
    lB[it] = &Bs[c * 512 + (size_t)lane * 8];
  }
  const int sxor = m_l & 7;

  floatx4 acc[4][4] = {};
  for (int ks = ks0; ks < ks1; ++ks){
    int k0 = ks << 6;
    int kk = k0 + colc;
    __syncthreads();
    #pragma unroll
    for (int it = 0; it < 4; ++it) gload_lds16(gA[it] + k0, lA[it]);
    #pragma unroll
    for (int it = 0; it < 4; ++it){
      uint4 u;
      if (kk + 8 <= Kb){
        const float4* p = reinterpret_cast<const float4*>(gBf[it] + kk);
        float4 x0 = p[0], x1 = p[1];
        u.x = f2bf2(x0.x, x0.y); u.y = f2bf2(x0.z, x0.w);
        u.z = f2bf2(x1.x, x1.y); u.w = f2bf2(x1.z, x1.w);
      } else {
        u.x = u.y = u.z = u.w = 0u;
      }
      *reinterpret_cast<uint4*>(lB[it]) = u;
    }
    __syncthreads();
    #pragma unroll
    for (int half = 0; half < 2; ++half){
      const int scol = ((half * 4 + q) ^ sxor) * 8;
      short8 af[4], bfr[4];
      #pragma unroll
      for (int i = 0; i < 4; ++i){
        af[i]  = *reinterpret_cast<const short8*>(&As[(wr + i * 16 + m_l) * 64 + scol]);
        bfr[i] = *reinterpret_cast<const short8*>(&Bs[(wc + i * 16 + m_l) * 64 + scol]);
      }
      #pragma unroll
      for (int mi = 0; mi < 4; ++mi)
        #pragma unroll
        for (int ni = 0; ni < 4; ++ni)
          acc[mi][ni] = __builtin_amdgcn_mfma_f32_16x16x32_bf16(af[mi], bfr[ni], acc[mi][ni], 0, 0, 0);
    }
  }

  float* Pz = P + (size_t)z * M * N;
  #pragma unroll
  for (int mi = 0; mi < 4; ++mi){
    int row0 = bm + wr + mi * 16 + q * 4;
    #pragma unroll
    for (int r = 0; r < 4; ++r){
      int row = row0 + r;
      if (row < M){
        #pragma unroll
        for (int ni = 0; ni < 4; ++ni){
          int col = bn + wc + ni * 16 + m_l;
          if (col < N) Pz[(size_t)row * N + col] = acc[mi][ni][r];
        }
      }
    }
  }
}

// ---------------- reduce split partials + bias + colstats (GCN2 path, N=192) ----------------
__global__ __launch_bounds__(256)
void reduce_split_bias_stats(const float* __restrict__ P, const float* __restrict__ bias,
                             float* __restrict__ out, float* __restrict__ ssum, float* __restrict__ ssq,
                             int MN, int N, int Z){
  __shared__ float lsum[192], lsq[192];
  int tid = threadIdx.x;
  if (tid < 192){ lsum[tid] = 0.f; lsq[tid] = 0.f; }
  __syncthreads();
  int i4 = (blockIdx.x * blockDim.x + tid) * 4;
  if (i4 < MN){
    const float4 bv = *reinterpret_cast<const float4*>(bias + (i4 % N));
    float4 s = bv;
    for (int z = 0; z < Z; ++z){
      const float4 p = *reinterpret_cast<const float4*>(P + (size_t)z * MN + i4);
      s.x += p.x; s.y += p.y; s.z += p.z; s.w += p.w;
    }
    *reinterpret_cast<float4*>(out + i4) = s;
    int c0 = i4 % N;
    atomicAdd(&lsum[c0],     s.x); atomicAdd(&lsq[c0],     s.x * s.x);
    atomicAdd(&lsum[c0 + 1], s.y); atomicAdd(&lsq[c0 + 1], s.y * s.y);
    atomicAdd(&lsum[c0 + 2], s.z); atomicAdd(&lsq[c0 + 2], s.z * s.z);
    atomicAdd(&lsum[c0 + 3], s.w); atomicAdd(&lsq[c0 + 3], s.w * s.w);
  }
  __syncthreads();
  if (tid < 192){ atomicAdd(&ssum[tid], lsum[tid]); atomicAdd(&ssq[tid], lsq[tid]); }
}

// ---------------- persistent LSTM: reg f16 weights, fused split-K reduce + segstats, P prefetch ----------------
template <int H2C, int BLK, int Z>
__global__ __launch_bounds__(BLK)
void lstm_kernel(const float* __restrict__ P, const float* __restrict__ bias,
                 const half2_t* __restrict__ Wp, float* __restrict__ out,
                 float* __restrict__ ssum, float* __restrict__ ssq,
                 int S, int MN){
  constexpr int H = 2 * H2C;
  constexpr int H4 = 4 * H;
  __shared__ _Float16 __attribute__((aligned(16))) hsh[H];
  __shared__ float gv[H4];
  __shared__ float ra[BLK / 64], rb[BLK / 64];
  const int b = blockIdx.x, t = threadIdx.x;
  const int lane = t & 63, wid = t >> 6;
  half2_t w[H2C];
  const half2_t* wp = Wp + t;
  #pragma unroll
  for (int j2 = 0; j2 < H2C; ++j2) w[j2] = wp[(size_t)j2 * H4];
  float cc = 0.f;
  if (t < H) hsh[t] = (_Float16)0.f;
  const float bval = bias[t];
  const size_t base = (size_t)b * S * H4 + t;
  float pv0[Z], pv1[Z];
  #pragma unroll
  for (int z = 0; z < Z; ++z) pv0[z] = P[(size_t)z * MN + base];
  #pragma unroll
  for (int z = 0; z < Z; ++z) pv1[z] = P[(size_t)z * MN + base + H4];
  __syncthreads();
  const half2_t* hp = reinterpret_cast<const half2_t*>(hsh);
  for (int s = 0; s < S; ++s){
    float pvn[Z];
    if (s + 2 < S){
      size_t o2 = base + (size_t)(s + 2) * H4;
      #pragma unroll
      for (int z = 0; z < Z; ++z) pvn[z] = P[(size_t)z * MN + o2];
    }
    float a0 = bval, a1 = 0.f, a2 = 0.f, a3 = 0.f;
    float a4 = 0.f, a5 = 0.f, a6 = 0.f, a7 = 0.f;
    #pragma unroll
    for (int z = 0; z < Z; ++z) a0 += pv0[z];
    #pragma unroll
    for (int j2 = 0; j2 < H2C; j2 += 8){
      a0 = dot2(w[j2],     hp[j2],     a0);
      a1 = dot2(w[j2 + 1], hp[j2 + 1], a1);
      a2 = dot2(w[j2 + 2], hp[j2 + 2], a2);
      a3 = dot2(w[j2 + 3], hp[j2 + 3], a3);
      a4 = dot2(w[j2 + 4], hp[j2 + 4], a4);
      a5 = dot2(w[j2 + 5], hp[j2 + 5], a5);
      a6 = dot2(w[j2 + 6], hp[j2 + 6], a6);
      a7 = dot2(w[j2 + 7], hp[j2 + 7], a7);
    }
    gv[t] = ((a0 + a1) + (a2 + a3)) + ((a4 + a5) + (a6 + a7));
    __syncthreads();
    float gvv = 0.f;
    if (t < H){
      float ig = sigf(gv[t]);
      float fg = sigf(gv[H + t]);
      float gg = tanhf(gv[2 * H + t]);
      float og = sigf(gv[3 * H + t]);
      cc = fg * cc + ig * gg;
      float hh = og * tanhf(cc);
      hsh[t] = (_Float16)hh;
      out[((size_t)b * S + s) * H + t] = hh;
      gvv = hh;
    }
    float q1 = gvv, q2 = gvv * gvv;
    for (int off2 = 32; off2; off2 >>= 1){ q1 += __shfl_down(q1, off2); q2 += __shfl_down(q2, off2); }
    if (lane == 0){ ra[wid] = q1; rb[wid] = q2; }
    __syncthreads();
    if (t == 0){
      float sa = 0.f, sb = 0.f;
      #pragma unroll
      for (int ww = 0; ww < BLK / 64; ++ww){ sa += ra[ww]; sb += rb[ww]; }
      atomicAdd(&ssum[s], sa);
      atomicAdd(&ssq[s], sb);
    }
    #pragma unroll
    for (int z = 0; z < Z; ++z){ pv0[z] = pv1[z]; pv1[z] = pvn[z]; }
  }
}

// ---------------- support2 with inline bnseg: A2mat[(nm*S+s)*25+v][k*96+c], stride 1280 ----------------
__global__ void support2_bn(const float* __restrict__ A, const float* __restrict__ lout,
                            const float* __restrict__ ssum, const float* __restrict__ ssq,
                            const float* __restrict__ g, const float* __restrict__ bb,
                            bf16_t* __restrict__ A2mat, int S, int cnt){
  int idx = blockIdx.x * blockDim.x + threadIdx.x;
  int total = 4 * S * 25 * 13 * 96;
  if (idx >= total) return;
  int c = idx % 96;
  int k = (idx / 96) % 13;
  int v = (idx / (96 * 13)) % 25;
  int rs = idx / (96 * 13 * 25);       // nm*S + s
  int s = rs % S, nm = rs / S;
  float mean = ssum[s] / cnt;
  float rstd = rsqrtf(ssq[s] / cnt - mean * mean + 1e-5f);
  float scale = rstd * g[s];
  float shift = bb[s] - mean * scale;
  const float* ar = A + (k * 25 + v) * 25;
  float acc = 0.f;
  #pragma unroll
  for (int u = 0; u < 25; ++u){
    float raw = lout[((size_t)(nm * 25 + u) * S + s) * 96 + c];
    acc += ar[u] * (raw * scale + shift);
  }
  A2mat[((size_t)rs * 25 + v) * 1280 + k * 96 + c] = f2bf(acc);
}

// ---------------- bnseg2 (from sums) + global pool ----------------
__global__ void pool_kernel(const float* __restrict__ lout2, const float* __restrict__ sum,
                            const float* __restrict__ sumsq, const float* __restrict__ g,
                            const float* __restrict__ bb, float* __restrict__ pooled,
                            int S, int H, int scnt){
  int n = blockIdx.x / H;
  int o = blockIdx.x % H;
  float acc = 0.f;
  int cnt = 2 * 25 * S;
  for (int i = threadIdx.x; i < cnt; i += 64){
    int m = i / (25 * S);
    int r = i % (25 * S);
    int v = r / S;
    int s = r % S;
    int b = (n * 2 + m) * 25 + v;
    float val = lout2[((size_t)b * S + s) * H + o];
    float mean = sum[s] / scnt;
    float rstd = rsqrtf(sumsq[s] / scnt - mean * mean + 1e-5f);
    val = (val - mean) * rstd * g[s] + bb[s];
    acc += val;
  }
  for (int off = 32; off; off >>= 1) acc += __shfl_down(acc, off);
  if (threadIdx.x == 0) pooled[n * H + o] = acc / cnt;
}

// ---------------- final FC ----------------
__global__ void fc_kernel(const float* __restrict__ pooled, const float* __restrict__ fcW,
                          const float* __restrict__ fcb, float* __restrict__ outp){
  int idx = blockIdx.x * blockDim.x + threadIdx.x;
  if (idx >= 120) return;
  int n = idx / 60, cls = idx % 60;
  float acc = fcb[cls];
  for (int o = 0; o < 192; ++o) acc += pooled[n * 192 + o] * fcW[cls * 192 + o];
  outp[idx] = acc;
}

// ---------------- host: replicate np.linspace + python round (ties-to-even) ----------------
static void make_segs(int T, int S, SegTable& tab, int& L){
  double step = (double)(T - 1) / (double)S;
  long long tv[51];
  for (int i = 0; i <= S; ++i){
    double v = 1.0 + step * (double)i;
    tv[i] = llrint(v);
  }
  L = 0;
  for (int s = 0; s < S; ++s){
    tab.st[s] = (int)tv[s] - 1;
    tab.en[s] = (int)tv[s + 1] - 1;
    int len = tab.en[s] - tab.st[s] + 1;
    if (len > L) L = len;
  }
  for (int s = S; s < 50; ++s){ tab.st[s] = 0; tab.en[s] = 0; }
  if (L > 4) L = 4;
}

extern "C" void kernel_launch(void* const* d_in, const int* in_sizes, int n_in,
                              void* d_out, int out_size, void* d_ws, size_t ws_size,
                              hipStream_t stream){
  const float* x         = (const float*)d_in[0];
  const float* data_bn_g = (const float*)d_in[2];
  const float* data_bn_b = (const float*)d_in[3];
  const float* A_powers1 = (const float*)d_in[4];
  const float* A_res1    = (const float*)d_in[5];
  const float* W1        = (const float*)d_in[6];
  const float* b1        = (const float*)d_in[7];
  const float* bn1_g     = (const float*)d_in[8];
  const float* bn1_b     = (const float*)d_in[9];
  const float* Wih1      = (const float*)d_in[10];
  const float* Whh1      = (const float*)d_in[11];
  const float* bih1      = (const float*)d_in[12];
  const float* bhh1      = (const float*)d_in[13];
  const float* bnseg1_g  = (const float*)d_in[14];
  const float* bnseg1_b  = (const float*)d_in[15];
  const float* A_powers2 = (const float*)d_in[16];
  const float* A_res2    = (const float*)d_in[17];
  const float* W2        = (const float*)d_in[18];
  const float* b2        = (const float*)d_in[19];
  const float* bn2_g     = (const float*)d_in[20];
  const float* bn2_b     = (const float*)d_in[21];
  const float* Wih2      = (const float*)d_in[22];
  const float* Whh2      = (const float*)d_in[23];
  const float* bih2      = (const float*)d_in[24];
  const float* bhh2      = (const float*)d_in[25];
  const float* bnseg2_g  = (const float*)d_in[26];
  const float* bnseg2_b  = (const float*)d_in[27];
  const float* fcW       = (const float*)d_in[28];
  const float* fcb       = (const float*)d_in[29];
  float* out = (float*)d_out;

  const int N = 2, C = 3, T = 100, V = 25, M = 2, NM = 4;
  const int C1 = 96, C2 = 192;
  const int S1 = 50, S2 = 30;
  const int B = 100;
  const int IN1 = 4752, IN2 = 18720;
  const int IN1P = 4800, IN2P = 18752;  // K padded to %64
  const int P1 = 4560, P2 = 18336;
  const int KG2 = 1248, KG2P = 1280;
  const int Z1 = 5, Z2 = 6, ZG = 4;

  size_t off = 0;
  char* base = (char*)d_ws;
  auto alloc = [&](size_t nbytes) -> void* {
    off = (off + 255) & ~(size_t)255;
    void* p = base + off;
    off += nbytes;
    return p;
  };
  float* A1full = (float*)alloc(325 * 25 * 4);
  float* A2full = (float*)alloc(325 * 25 * 4);
  float* h1     = (float*)alloc((size_t)NM * C * T * V * 4);
  float* y1mat  = (float*)alloc((size_t)NM * T * V * C1 * 4);
  float* stats  = (float*)alloc(736 * 4);
  float* st1a = stats, *st1b = stats + 96;
  float* sg1a = stats + 192, *sg1b = stats + 242;
  float* st2a = stats + 292, *st2b = stats + 484;
  float* sg2a = stats + 676, *sg2b = stats + 706;
  float* l1out  = (float*)alloc((size_t)B * S1 * C1 * 4);
  bf16_t* A2mat = (bf16_t*)alloc((size_t)NM * S1 * V * KG2P * 2);
  float* y2mat  = (float*)alloc((size_t)NM * S1 * V * C2 * 4);
  float* l2out  = (float*)alloc((size_t)B * S2 * C2 * 4);
  float* pooled = (float*)alloc(2 * C2 * 4);
  float* bias1  = (float*)alloc(4 * C1 * 4);
  float* bias2  = (float*)alloc(4 * C2 * 4);
  half2_t* Wp1  = (half2_t*)alloc((size_t)(C1 / 2) * 4 * C1 * 4);
  half2_t* Wp2  = (half2_t*)alloc((size_t)(C2 / 2) * 4 * C2 * 4);
  unsigned short* lut1 = (unsigned short*)alloc((size_t)P1 * 2);
  unsigned short* lut2 = (unsigned short*)alloc((size_t)P2 * 2);
  size_t pmax = (size_t)Z2 * 3000 * 768;
  {
    size_t p1s = (size_t)Z1 * 5000 * 384; if (p1s > pmax) pmax = p1s;
    size_t pgs = (size_t)ZG * 5000 * 192; if (pgs > pmax) pmax = pgs;
  }
  float* Pbuf = (float*)alloc(pmax * 4);
  bf16_t* feats = (bf16_t*)alloc((size_t)B * S2 * IN2P * 2);
  (void)ws_size; (void)in_sizes; (void)n_in; (void)out_size;

  // 1) prep: adds, whh packs, LUTs, stat zeros, A2mat K-pad
  prep_misc<<<625, 256, 0, stream>>>(A_powers1, A_res1, A1full, A_powers2, A_res2, A2full,
                                     bih1, bhh1, bias1, bih2, bhh2, bias2,
                                     Whh1, Wp1, Whh2, Wp2, lut1, lut2, stats, A2mat);

  // 2) data BN
  data_bn_kernel<<<M * V * C, 64, 0, stream>>>(x, data_bn_g, data_bn_b, h1, N, C, T, V, M);

  // 3) GCN1 fused (support + contract + stats)
  gcn1_fused<<<NM * T, 256, 0, stream>>>(A1full, h1, W1, b1, y1mat, st1a, st1b, T);

  SegTable seg1, seg2; int L1, L2;
  make_segs(T, S1, seg1, L1);
  make_segs(S1, S2, seg2, L2);

  // 4) feats1 (bn+relu inline)
  feats_bn_kernel<<<B * S1, 256, 0, stream>>>(y1mat, st1a, st1b, bn1_g, bn1_b, feats, seg1,
                                              (const unsigned int*)lut1, T, C1, S1, L1, P1, IN1P,
                                              NM * T * 25);
  // 5) xp1 GEMM (B = Wih1 fp32, converted in staging)
  {
    int Mm = B * S1, Nn = 4 * C1;
    dim3 g((Mm + 127) / 128, (Nn + 127) / 128, Z1);
    gemm_mfma_f32b<<<g, 256, 0, stream>>>(feats, Wih1, Pbuf, Mm, Nn, IN1P, IN1);
    // 6) lstm1 (+segstats fused)
    lstm_kernel<48, 384, Z1><<<B, 384, 0, stream>>>(Pbuf, bias1, Wp1, l1out, sg1a, sg1b, S1, Mm * Nn);
  }

  // 7) support2 (+bnseg inline)
  {
    int tot = NM * S1 * 25 * 13 * 96;
    support2_bn<<<(tot + 255) / 256, 256, 0, stream>>>(A2full, l1out, sg1a, sg1b, bnseg1_g,
                                                       bnseg1_b, A2mat, S1, B * C1);
  }
  // 8) GCN2 GEMM (B = W2 fp32)
  {
    int Mm = NM * S1 * 25, Nn = C2;
    dim3 g((Mm + 127) / 128, (Nn + 127) / 128, ZG);
    gemm_mfma_f32b<<<g, 256, 0, stream>>>(A2mat, W2, Pbuf, Mm, Nn, KG2P, KG2);
    // 9) reduce + bias + colstats
    int MN = Mm * Nn;
    reduce_split_bias_stats<<<(MN / 4 + 255) / 256, 256, 0, stream>>>(Pbuf, b2, y2mat, st2a, st2b,
                                                                      MN, Nn, ZG);
  }

  // 10) feats2 (bn+relu inline)
  feats_bn_kernel<<<B * S2, 256, 0, stream>>>(y2mat, st2a, st2b, bn2_g, bn2_b, feats, seg2,
                                              (const unsigned int*)lut2, S1, C2, S2, L2, P2, IN2P,
                                              NM * S1 * 25);
  // 11) xp2 GEMM (B = Wih2 fp32)
  {
    int Mm = B * S2, Nn = 4 * C2;
    dim3 g((Mm + 127) / 128, (Nn + 127) / 128, Z2);
    gemm_mfma_f32b<<<g, 256, 0, stream>>>(feats, Wih2, Pbuf, Mm, Nn, IN2P, IN2);
    // 12) lstm2 (+segstats fused)
    lstm_kernel<96, 768, Z2><<<B, 768, 0, stream>>>(Pbuf, bias2, Wp2, l2out, sg2a, sg2b, S2, Mm * Nn);
  }

  // 13) pool, 14) fc
  pool_kernel<<<2 * C2, 64, 0, stream>>>(l2out, sg2a, sg2b, bnseg2_g, bnseg2_b, pooled, S2, C2, B * C2);
  fc_kernel<<<1, 128, 0, stream>>>(pooled, fcW, fcb, out);
}

// Round 8
// 679.317 us; speedup vs baseline: 1.1526x; 1.1526x over previous
//
#include <hip/hip_runtime.h>
#include <cmath>
#include <cstdint>
#include <cstddef>

typedef unsigned short bf16_t;
typedef __attribute__((ext_vector_type(8))) short short8;
typedef __attribute__((ext_vector_type(4))) float floatx4;
typedef __attribute__((ext_vector_type(2))) _Float16 half2_t;

__device__ __forceinline__ float bf2f(bf16_t b){
  unsigned int u = ((unsigned int)b) << 16;
  return __uint_as_float(u);
}
__device__ __forceinline__ bf16_t f2bf(float f){
  unsigned int u = __float_as_uint(f);
  unsigned int r = (u + 0x7fffu + ((u >> 16) & 1u)) >> 16;  // RNE
  return (bf16_t)r;
}
__device__ __forceinline__ unsigned int f2bf2(float a, float b){
  return (unsigned int)f2bf(a) | ((unsigned int)f2bf(b) << 16);
}
__device__ __forceinline__ float sigf(float x){ return 1.0f / (1.0f + expf(-x)); }

__device__ __forceinline__ float dot2(half2_t a, half2_t b, float c){
#if __has_builtin(__builtin_amdgcn_fdot2)
  return __builtin_amdgcn_fdot2(a, b, c, false);
#else
  return c + (float)a.x * (float)b.x + (float)a.y * (float)b.y;
#endif
}

__device__ __forceinline__ void gload_lds16(const bf16_t* g, bf16_t* lds){
  __builtin_amdgcn_global_load_lds(
      (const __attribute__((address_space(1))) unsigned int*)g,
      (__attribute__((address_space(3))) unsigned int*)lds, 16, 0, 0);
}

// ---------------- mega prep kernel: adds, whh pack, LUTs, stat zero, A2mat K-pad ----------------
__global__ void prep_misc(const float* __restrict__ a1, const float* __restrict__ r1, float* __restrict__ o1,
                          const float* __restrict__ a2, const float* __restrict__ r2, float* __restrict__ o2,
                          const float* __restrict__ bi1, const float* __restrict__ bh1, float* __restrict__ ob1,
                          const float* __restrict__ bi2, const float* __restrict__ bh2, float* __restrict__ ob2,
                          const float* __restrict__ Whh1, half2_t* __restrict__ Wp1,
                          const float* __restrict__ Whh2, half2_t* __restrict__ Wp2,
                          unsigned short* __restrict__ lut1, unsigned short* __restrict__ lut2,
                          float* __restrict__ stats, bf16_t* __restrict__ A2mat){
  int i = blockIdx.x * blockDim.x + threadIdx.x;
  if (i < 8125){ o1[i] = a1[i] + r1[i]; o2[i] = a2[i] + r2[i]; }
  if (i < 384) ob1[i] = bi1[i] + bh1[i];
  if (i < 768) ob2[i] = bi2[i] + bh2[i];
  if (i < 736) stats[i] = 0.f;
  if (i < 18432){                       // pack Whh1 (H=96): Wp[j2*384+t]
    int t = i % 384, j2 = i / 384;
    half2_t w; w.x = (_Float16)Whh1[(size_t)t * 96 + 2 * j2];
    w.y = (_Float16)Whh1[(size_t)t * 96 + 2 * j2 + 1];
    Wp1[i] = w;
  }
  if (i < 73728){                       // pack Whh2 (H=192)
    int t = i % 768, j2 = i / 768;
    half2_t w; w.x = (_Float16)Whh2[(size_t)t * 192 + 2 * j2];
    w.y = (_Float16)Whh2[(size_t)t * 192 + 2 * j2 + 1];
    Wp2[i] = w;
  }
  // levy pair LUTs: flat p -> (i<<8)|j
  if (i < 4560){
    int d = 96, p = i;
    int r = (int)(((2.0 * d - 1.0) - sqrt((2.0 * d - 1.0) * (2.0 * d - 1.0) - 8.0 * (double)p)) * 0.5);
    if (r < 0) r = 0;
    while (r + 1 <= d - 2 && (r + 1) * (d - 1) - ((r + 1) * r) / 2 <= p) ++r;
    while (r > 0 && r * (d - 1) - (r * (r - 1)) / 2 > p) --r;
    int jj = p - (r * (d - 1) - (r * (r - 1)) / 2);
    lut1[p] = (unsigned short)((r << 8) | (r + 1 + jj));
  }
  if (i < 18336){
    int d = 192, p = i;
    int r = (int)(((2.0 * d - 1.0) - sqrt((2.0 * d - 1.0) * (2.0 * d - 1.0) - 8.0 * (double)p)) * 0.5);
    if (r < 0) r = 0;
    while (r + 1 <= d - 2 && (r + 1) * (d - 1) - ((r + 1) * r) / 2 <= p) ++r;
    while (r > 0 && r * (d - 1) - (r * (r - 1)) / 2 > p) --r;
    int jj = p - (r * (d - 1) - (r * (r - 1)) / 2);
    lut2[p] = (unsigned short)((r << 8) | (r + 1 + jj));
  }
  if (i < 160000){                      // A2mat K-pad cols [1248,1280), 5000 rows
    int row = i >> 5, col = 1248 + (i & 31);
    A2mat[(size_t)row * 1280 + col] = 0;
  }
}

// ---------------- three fp32->bf16 pad conversions in ONE dispatch ----------------
__device__ __forceinline__ void f2bf_seg(const float* in, bf16_t* out, int Kin, int Kout, int li){
  int ko8 = Kout >> 3;
  int r = li / ko8, k8 = (li % ko8) << 3;
  uint4 u;
  if (k8 + 8 <= Kin){
    const float4* p = reinterpret_cast<const float4*>(in + (size_t)r * Kin + k8);
    float4 x0 = p[0], x1 = p[1];
    u.x = f2bf2(x0.x, x0.y); u.y = f2bf2(x0.z, x0.w);
    u.z = f2bf2(x1.x, x1.y); u.w = f2bf2(x1.z, x1.w);
  } else {
    u.x = u.y = u.z = u.w = 0u;
  }
  *reinterpret_cast<uint4*>(out + (size_t)r * Kout + k8) = u;
}

__global__ void f2bf_pad8_3(const float* __restrict__ in1, bf16_t* __restrict__ out1, int Kin1, int Kout1, int c1,
                            const float* __restrict__ in2, bf16_t* __restrict__ out2, int Kin2, int Kout2, int c2,
                            const float* __restrict__ in3, bf16_t* __restrict__ out3, int Kin3, int Kout3, int c3){
  int idx = blockIdx.x * blockDim.x + threadIdx.x;
  if (idx < c1){ f2bf_seg(in1, out1, Kin1, Kout1, idx); return; }
  idx -= c1;
  if (idx < c2){ f2bf_seg(in2, out2, Kin2, Kout2, idx); return; }
  idx -= c2;
  if (idx < c3) f2bf_seg(in3, out3, Kin3, Kout3, idx);
}

// ---------------- data batchnorm: x(N,C,T,V,M) -> h1[(nm*C+c)*T+t][V] ----------------
__global__ void data_bn_kernel(const float* __restrict__ x, const float* __restrict__ g,
                               const float* __restrict__ bb, float* __restrict__ h1,
                               int N, int C, int T, int V, int M){
  int ch = blockIdx.x;             // (m*V + v)*C + c
  int m = ch / (V * C);
  int v = (ch / C) % V;
  int c = ch % C;
  int tid = threadIdx.x;
  int cnt = N * T;
  float s = 0.f, s2 = 0.f;
  for (int i = tid; i < cnt; i += 64){
    int n = i / T, t = i % T;
    float val = x[(((size_t)(n * C + c) * T + t) * V + v) * M + m];
    s += val; s2 += val * val;
  }
  for (int off = 32; off; off >>= 1){ s += __shfl_down(s, off); s2 += __shfl_down(s2, off); }
  s = __shfl(s, 0); s2 = __shfl(s2, 0);
  float mean = s / cnt;
  float rstd = rsqrtf(s2 / cnt - mean * mean + 1e-5f);
  float gg = g[ch], bo = bb[ch];
  for (int i = tid; i < cnt; i += 64){
    int n = i / T, t = i % T;
    float val = x[(((size_t)(n * C + c) * T + t) * V + v) * M + m];
    float y = (val - mean) * rstd * gg + bo;
    h1[((size_t)((n * M + m) * C + c) * T + t) * V + v] = y;
  }
}

// ---------------- GCN1 fused: support + W-contract + colstats. block = (nm,t) ----------------
__global__ __launch_bounds__(256)
void gcn1_fused(const float* __restrict__ A, const float* __restrict__ h1,
                const float* __restrict__ W1, const float* __restrict__ b1,
                float* __restrict__ y1, float* __restrict__ ssum, float* __restrict__ ssq, int T){
  __shared__ float h[3][25];
  __shared__ float sup[3][325];
  __shared__ float lsum[96], lsq[96];
  int blk = blockIdx.x;
  int nm = blk / T, t = blk % T;
  int tid = threadIdx.x;
  if (tid < 75){
    int c = tid / 25, v = tid % 25;
    h[c][v] = h1[((size_t)(nm * 3 + c) * T + t) * 25 + v];
  }
  if (tid < 96){ lsum[tid] = 0.f; lsq[tid] = 0.f; }
  __syncthreads();
  for (int w = tid; w < 975; w += 256){
    int c = w / 325, ww = w % 325;
    const float* ar = A + ww * 25;
    float acc = 0.f;
    #pragma unroll
    for (int u = 0; u < 25; ++u) acc += ar[u] * h[c][u];
    sup[c][ww] = acc;
  }
  __syncthreads();
  for (int o2 = tid; o2 < 2400; o2 += 256){
    int v = o2 / 96, o = o2 % 96;
    float acc = b1[o];
    #pragma unroll
    for (int k = 0; k < 13; ++k)
      #pragma unroll
      for (int c = 0; c < 3; ++c)
        acc += W1[o * 39 + k * 3 + c] * sup[c][k * 25 + v];
    y1[((size_t)blk * 25 + v) * 96 + o] = acc;
    atomicAdd(&lsum[o], acc);
    atomicAdd(&lsq[o], acc * acc);
  }
  __syncthreads();
  if (tid < 96){ atomicAdd(&ssum[tid], lsum[tid]); atomicAdd(&ssq[tid], lsq[tid]); }
}

// ---------------- feats with inline BN+relu: reads y-mat + stats, writes bf16 rows ----------------
struct SegTable { int st[50]; int en[50]; };

__global__ void feats_bn_kernel(const float* __restrict__ ymat, const float* __restrict__ sum,
                                const float* __restrict__ sumsq, const float* __restrict__ g,
                                const float* __restrict__ bb, bf16_t* __restrict__ feats,
                                SegTable segs, const unsigned int* __restrict__ lut32,
                                int T, int d, int S, int L, int pairs, int rowlenP, int R){
  __shared__ float pts[4][192];
  int bs = blockIdx.x;
  int b = bs / S, s = bs % S;
  int nm = b / 25, v = b % 25;
  int st = segs.st[s], en = segs.en[s];
  int nt = blockDim.x, tid = threadIdx.x;
  for (int l = 0; l < L; ++l){
    int t = st + l; if (t > en) t = en;
    const float* yrow = ymat + ((size_t)(nm * T + t) * 25 + v) * d;
    for (int i = tid; i < d; i += nt){
      float mean = sum[i] / R;
      float rstd = rsqrtf(sumsq[i] / R - mean * mean + 1e-5f);
      pts[l][i] = fmaxf((yrow[i] - mean) * rstd * g[i] + bb[i], 0.f);
    }
  }
  __syncthreads();
  unsigned int* frow32 = reinterpret_cast<unsigned int*>(feats + (size_t)bs * rowlenP);
  int d2 = d >> 1;
  for (int i2 = tid; i2 < d2; i2 += nt){
    int i = 2 * i2;
    frow32[i2]      = f2bf2(pts[0][i], pts[0][i + 1]);
    frow32[d2 + i2] = f2bf2(pts[L - 1][i] - pts[0][i], pts[L - 1][i + 1] - pts[0][i + 1]);
  }
  int rowlen2 = (2 * d + pairs) >> 1, rowlenP2 = rowlenP >> 1;
  for (int i = tid + rowlen2; i < rowlenP2; i += nt) frow32[i] = 0;  // K pad
  int Lm2 = L - 2;
  unsigned int* lrow32 = frow32 + d;
  int pairs2 = pairs >> 1;
  for (int p2 = tid; p2 < pairs2; p2 += nt){
    unsigned int ee = lut32[p2];
    int i0 = (ee >> 8) & 255, j0 = ee & 255;
    int i1 = ee >> 24, j1 = (ee >> 16) & 255;
    float acc0 = 0.f, acc1 = 0.f;
    for (int l = 1; l <= Lm2; ++l){
      float ri = pts[l][i0] - pts[0][i0], rj = pts[l][j0] - pts[0][j0];
      float di = pts[l + 1][i0] - pts[l][i0], dj = pts[l + 1][j0] - pts[l][j0];
      acc0 += ri * dj - rj * di;
      float ri1 = pts[l][i1] - pts[0][i1], rj1 = pts[l][j1] - pts[0][j1];
      float di1 = pts[l + 1][i1] - pts[l][i1], dj1 = pts[l + 1][j1] - pts[l][j1];
      acc1 += ri1 * dj1 - rj1 * di1;
    }
    lrow32[p2] = f2bf2(0.5f * acc0, 0.5f * acc1);
  }
}

// ---------------- split-K MFMA bf16 NT GEMM, BK=64, XOR-swizzled LDS ----------------
__global__ __launch_bounds__(256)
void gemm_mfma_nt_split(const bf16_t* __restrict__ A, const bf16_t* __restrict__ B,
                        float* __restrict__ P, int M, int N, int K){
  __shared__ bf16_t As[128 * 64];
  __shared__ bf16_t Bs[128 * 64];
  const int tid = threadIdx.x;
  const int lane = tid & 63, wv = tid >> 6;
  const int bm = blockIdx.x * 128, bn = blockIdx.y * 128;
  const int wr = (wv >> 1) * 64, wc = (wv & 1) * 64;
  const int m_l = lane & 15, q = lane >> 4;

  const int ksteps = K >> 6;
  const int Z = gridDim.z, z = blockIdx.z;
  const int per = (ksteps + Z - 1) / Z;
  const int ks0 = z * per;
  const int ks1 = (ks0 + per < ksteps) ? ks0 + per : ksteps;

  const int rlane = lane >> 3;
  const int slane = lane & 7;
  const int colc = (slane ^ rlane) * 8;
  const bf16_t* gA[4]; const bf16_t* gB[4];
  bf16_t* lA[4]; bf16_t* lB[4];
  #pragma unroll
  for (int it = 0; it < 4; ++it){
    int c = it * 4 + wv;
    int rowA = bm + c * 8 + rlane; if (rowA > M - 1) rowA = M - 1;
    int rowB = bn + c * 8 + rlane; if (rowB > N - 1) rowB = N - 1;
    gA[it] = A + (size_t)rowA * K + colc;
    gB[it] = B + (size_t)rowB * K + colc;
    lA[it] = &As[c * 512];
    lB[it] = &Bs[c * 512];
  }
  const int sxor = m_l & 7;

  floatx4 acc[4][4] = {};
  for (int ks = ks0; ks < ks1; ++ks){
    int k0 = ks << 6;
    __syncthreads();
    #pragma unroll
    for (int it = 0; it < 4; ++it){
      gload_lds16(gA[it] + k0, lA[it]);
      gload_lds16(gB[it] + k0, lB[it]);
    }
    __syncthreads();
    #pragma unroll
    for (int half = 0; half < 2; ++half){
      const int scol = ((half * 4 + q) ^ sxor) * 8;
      short8 af[4], bfr[4];
      #pragma unroll
      for (int i = 0; i < 4; ++i){
        af[i]  = *reinterpret_cast<const short8*>(&As[(wr + i * 16 + m_l) * 64 + scol]);
        bfr[i] = *reinterpret_cast<const short8*>(&Bs[(wc + i * 16 + m_l) * 64 + scol]);
      }
      #pragma unroll
      for (int mi = 0; mi < 4; ++mi)
        #pragma unroll
        for (int ni = 0; ni < 4; ++ni)
          acc[mi][ni] = __builtin_amdgcn_mfma_f32_16x16x32_bf16(af[mi], bfr[ni], acc[mi][ni], 0, 0, 0);
    }
  }

  float* Pz = P + (size_t)z * M * N;
  #pragma unroll
  for (int mi = 0; mi < 4; ++mi){
    int row0 = bm + wr + mi * 16 + q * 4;
    #pragma unroll
    for (int r = 0; r < 4; ++r){
      int row = row0 + r;
      if (row < M){
        #pragma unroll
        for (int ni = 0; ni < 4; ++ni){
          int col = bn + wc + ni * 16 + m_l;
          if (col < N) Pz[(size_t)row * N + col] = acc[mi][ni][r];
        }
      }
    }
  }
}

// ---------------- reduce split partials + bias + colstats (GCN2 path, N=192) ----------------
__global__ __launch_bounds__(256)
void reduce_split_bias_stats(const float* __restrict__ P, const float* __restrict__ bias,
                             float* __restrict__ out, float* __restrict__ ssum, float* __restrict__ ssq,
                             int MN, int N, int Z){
  __shared__ float lsum[192], lsq[192];
  int tid = threadIdx.x;
  if (tid < 192){ lsum[tid] = 0.f; lsq[tid] = 0.f; }
  __syncthreads();
  int i4 = (blockIdx.x * blockDim.x + tid) * 4;
  if (i4 < MN){
    const float4 bv = *reinterpret_cast<const float4*>(bias + (i4 % N));
    float4 s = bv;
    for (int z = 0; z < Z; ++z){
      const float4 p = *reinterpret_cast<const float4*>(P + (size_t)z * MN + i4);
      s.x += p.x; s.y += p.y; s.z += p.z; s.w += p.w;
    }
    *reinterpret_cast<float4*>(out + i4) = s;
    int c0 = i4 % N;
    atomicAdd(&lsum[c0],     s.x); atomicAdd(&lsq[c0],     s.x * s.x);
    atomicAdd(&lsum[c0 + 1], s.y); atomicAdd(&lsq[c0 + 1], s.y * s.y);
    atomicAdd(&lsum[c0 + 2], s.z); atomicAdd(&lsq[c0 + 2], s.z * s.z);
    atomicAdd(&lsum[c0 + 3], s.w); atomicAdd(&lsq[c0 + 3], s.w * s.w);
  }
  __syncthreads();
  if (tid < 192){ atomicAdd(&ssum[tid], lsum[tid]); atomicAdd(&ssq[tid], lsq[tid]); }
}

// ---------------- persistent LSTM: reg f16 weights, fused split-K reduce + segstats, P prefetch ----------------
template <int H2C, int BLK, int Z>
__global__ __launch_bounds__(BLK)
void lstm_kernel(const float* __restrict__ P, const float* __restrict__ bias,
                 const half2_t* __restrict__ Wp, float* __restrict__ out,
                 float* __restrict__ ssum, float* __restrict__ ssq,
                 int S, int MN){
  constexpr int H = 2 * H2C;
  constexpr int H4 = 4 * H;
  __shared__ _Float16 __attribute__((aligned(16))) hsh[H];
  __shared__ float gv[H4];
  __shared__ float ra[BLK / 64], rb[BLK / 64];
  const int b = blockIdx.x, t = threadIdx.x;
  const int lane = t & 63, wid = t >> 6;
  half2_t w[H2C];
  const half2_t* wp = Wp + t;
  #pragma unroll
  for (int j2 = 0; j2 < H2C; ++j2) w[j2] = wp[(size_t)j2 * H4];
  float cc = 0.f;
  if (t < H) hsh[t] = (_Float16)0.f;
  const float bval = bias[t];
  const size_t base = (size_t)b * S * H4 + t;
  float pv0[Z], pv1[Z];
  #pragma unroll
  for (int z = 0; z < Z; ++z) pv0[z] = P[(size_t)z * MN + base];
  #pragma unroll
  for (int z = 0; z < Z; ++z) pv1[z] = P[(size_t)z * MN + base + H4];
  __syncthreads();
  const half2_t* hp = reinterpret_cast<const half2_t*>(hsh);
  for (int s = 0; s < S; ++s){
    float pvn[Z];
    if (s + 2 < S){
      size_t o2 = base + (size_t)(s + 2) * H4;
      #pragma unroll
      for (int z = 0; z < Z; ++z) pvn[z] = P[(size_t)z * MN + o2];
    }
    float a0 = bval, a1 = 0.f, a2 = 0.f, a3 = 0.f;
    float a4 = 0.f, a5 = 0.f, a6 = 0.f, a7 = 0.f;
    #pragma unroll
    for (int z = 0; z < Z; ++z) a0 += pv0[z];
    #pragma unroll
    for (int j2 = 0; j2 < H2C; j2 += 8){
      a0 = dot2(w[j2],     hp[j2],     a0);
      a1 = dot2(w[j2 + 1], hp[j2 + 1], a1);
      a2 = dot2(w[j2 + 2], hp[j2 + 2], a2);
      a3 = dot2(w[j2 + 3], hp[j2 + 3], a3);
      a4 = dot2(w[j2 + 4], hp[j2 + 4], a4);
      a5 = dot2(w[j2 + 5], hp[j2 + 5], a5);
      a6 = dot2(w[j2 + 6], hp[j2 + 6], a6);
      a7 = dot2(w[j2 + 7], hp[j2 + 7], a7);
    }
    gv[t] = ((a0 + a1) + (a2 + a3)) + ((a4 + a5) + (a6 + a7));
    __syncthreads();
    float gvv = 0.f;
    if (t < H){
      float ig = sigf(gv[t]);
      float fg = sigf(gv[H + t]);
      float gg = tanhf(gv[2 * H + t]);
      float og = sigf(gv[3 * H + t]);
      cc = fg * cc + ig * gg;
      float hh = og * tanhf(cc);
      hsh[t] = (_Float16)hh;
      out[((size_t)b * S + s) * H + t] = hh;
      gvv = hh;
    }
    float q1 = gvv, q2 = gvv * gvv;
    for (int off2 = 32; off2; off2 >>= 1){ q1 += __shfl_down(q1, off2); q2 += __shfl_down(q2, off2); }
    if (lane == 0){ ra[wid] = q1; rb[wid] = q2; }
    __syncthreads();
    if (t == 0){
      float sa = 0.f, sb = 0.f;
      #pragma unroll
      for (int ww = 0; ww < BLK / 64; ++ww){ sa += ra[ww]; sb += rb[ww]; }
      atomicAdd(&ssum[s], sa);
      atomicAdd(&ssq[s], sb);
    }
    #pragma unroll
    for (int z = 0; z < Z; ++z){ pv0[z] = pv1[z]; pv1[z] = pvn[z]; }
  }
}

// ---------------- support2 with inline bnseg: A2mat[(nm*S+s)*25+v][k*96+c], stride 1280 ----------------
__global__ void support2_bn(const float* __restrict__ A, const float* __restrict__ lout,
                            const float* __restrict__ ssum, const float* __restrict__ ssq,
                            const float* __restrict__ g, const float* __restrict__ bb,
                            bf16_t* __restrict__ A2mat, int S, int cnt){
  int idx = blockIdx.x * blockDim.x + threadIdx.x;
  int total = 4 * S * 25 * 13 * 96;
  if (idx >= total) return;
  int c = idx % 96;
  int k = (idx / 96) % 13;
  int v = (idx / (96 * 13)) % 25;
  int rs = idx / (96 * 13 * 25);       // nm*S + s
  int s = rs % S, nm = rs / S;
  float mean = ssum[s] / cnt;
  float rstd = rsqrtf(ssq[s] / cnt - mean * mean + 1e-5f);
  float scale = rstd * g[s];
  float shift = bb[s] - mean * scale;
  const float* ar = A + (k * 25 + v) * 25;
  float acc = 0.f;
  #pragma unroll
  for (int u = 0; u < 25; ++u){
    float raw = lout[((size_t)(nm * 25 + u) * S + s) * 96 + c];
    acc += ar[u] * (raw * scale + shift);
  }
  A2mat[((size_t)rs * 25 + v) * 1280 + k * 96 + c] = f2bf(acc);
}

// ---------------- bnseg2 (from sums) + global pool ----------------
__global__ void pool_kernel(const float* __restrict__ lout2, const float* __restrict__ sum,
                            const float* __restrict__ sumsq, const float* __restrict__ g,
                            const float* __restrict__ bb, float* __restrict__ pooled,
                            int S, int H, int scnt){
  int n = blockIdx.x / H;
  int o = blockIdx.x % H;
  float acc = 0.f;
  int cnt = 2 * 25 * S;
  for (int i = threadIdx.x; i < cnt; i += 64){
    int m = i / (25 * S);
    int r = i % (25 * S);
    int v = r / S;
    int s = r % S;
    int b = (n * 2 + m) * 25 + v;
    float val = lout2[((size_t)b * S + s) * H + o];
    float mean = sum[s] / scnt;
    float rstd = rsqrtf(sumsq[s] / scnt - mean * mean + 1e-5f);
    val = (val - mean) * rstd * g[s] + bb[s];
    acc += val;
  }
  for (int off = 32; off; off >>= 1) acc += __shfl_down(acc, off);
  if (threadIdx.x == 0) pooled[n * H + o] = acc / cnt;
}

// ---------------- final FC ----------------
__global__ void fc_kernel(const float* __restrict__ pooled, const float* __restrict__ fcW,
                          const float* __restrict__ fcb, float* __restrict__ outp){
  int idx = blockIdx.x * blockDim.x + threadIdx.x;
  if (idx >= 120) return;
  int n = idx / 60, cls = idx % 60;
  float acc = fcb[cls];
  for (int o = 0; o < 192; ++o) acc += pooled[n * 192 + o] * fcW[cls * 192 + o];
  outp[idx] = acc;
}

// ---------------- host: replicate np.linspace + python round (ties-to-even) ----------------
static void make_segs(int T, int S, SegTable& tab, int& L){
  double step = (double)(T - 1) / (double)S;
  long long tv[51];
  for (int i = 0; i <= S; ++i){
    double v = 1.0 + step * (double)i;
    tv[i] = llrint(v);
  }
  L = 0;
  for (int s = 0; s < S; ++s){
    tab.st[s] = (int)tv[s] - 1;
    tab.en[s] = (int)tv[s + 1] - 1;
    int len = tab.en[s] - tab.st[s] + 1;
    if (len > L) L = len;
  }
  for (int s = S; s < 50; ++s){ tab.st[s] = 0; tab.en[s] = 0; }
  if (L > 4) L = 4;
}

extern "C" void kernel_launch(void* const* d_in, const int* in_sizes, int n_in,
                              void* d_out, int out_size, void* d_ws, size_t ws_size,
                              hipStream_t stream){
  const float* x         = (const float*)d_in[0];
  const float* data_bn_g = (const float*)d_in[2];
  const float* data_bn_b = (const float*)d_in[3];
  const float* A_powers1 = (const float*)d_in[4];
  const float* A_res1    = (const float*)d_in[5];
  const float* W1        = (const float*)d_in[6];
  const float* b1        = (const float*)d_in[7];
  const float* bn1_g     = (const float*)d_in[8];
  const float* bn1_b     = (const float*)d_in[9];
  const float* Wih1      = (const float*)d_in[10];
  const float* Whh1      = (const float*)d_in[11];
  const float* bih1      = (const float*)d_in[12];
  const float* bhh1      = (const float*)d_in[13];
  const float* bnseg1_g  = (const float*)d_in[14];
  const float* bnseg1_b  = (const float*)d_in[15];
  const float* A_powers2 = (const float*)d_in[16];
  const float* A_res2    = (const float*)d_in[17];
  const float* W2        = (const float*)d_in[18];
  const float* b2        = (const float*)d_in[19];
  const float* bn2_g     = (const float*)d_in[20];
  const float* bn2_b     = (const float*)d_in[21];
  const float* Wih2      = (const float*)d_in[22];
  const float* Whh2      = (const float*)d_in[23];
  const float* bih2      = (const float*)d_in[24];
  const float* bhh2      = (const float*)d_in[25];
  const float* bnseg2_g  = (const float*)d_in[26];
  const float* bnseg2_b  = (const float*)d_in[27];
  const float* fcW       = (const float*)d_in[28];
  const float* fcb       = (const float*)d_in[29];
  float* out = (float*)d_out;

  const int N = 2, C = 3, T = 100, V = 25, M = 2, NM = 4;
  const int C1 = 96, C2 = 192;
  const int S1 = 50, S2 = 30;
  const int B = 100;
  const int IN1 = 4752, IN2 = 18720;
  const int IN1P = 4800, IN2P = 18752;  // K padded to %64
  const int P1 = 4560, P2 = 18336;
  const int KG2 = 1248, KG2P = 1280;
  const int Z1 = 5, Z2 = 6, ZG = 4;

  size_t off = 0;
  char* base = (char*)d_ws;
  auto alloc = [&](size_t nbytes) -> void* {
    off = (off + 255) & ~(size_t)255;
    void* p = base + off;
    off += nbytes;
    return p;
  };
  float* A1full = (float*)alloc(325 * 25 * 4);
  float* A2full = (float*)alloc(325 * 25 * 4);
  float* h1     = (float*)alloc((size_t)NM * C * T * V * 4);
  float* y1mat  = (float*)alloc((size_t)NM * T * V * C1 * 4);
  float* stats  = (float*)alloc(736 * 4);
  float* st1a = stats, *st1b = stats + 96;
  float* sg1a = stats + 192, *sg1b = stats + 242;
  float* st2a = stats + 292, *st2b = stats + 484;
  float* sg2a = stats + 676, *sg2b = stats + 706;
  float* l1out  = (float*)alloc((size_t)B * S1 * C1 * 4);
  bf16_t* A2mat = (bf16_t*)alloc((size_t)NM * S1 * V * KG2P * 2);
  float* y2mat  = (float*)alloc((size_t)NM * S1 * V * C2 * 4);
  float* l2out  = (float*)alloc((size_t)B * S2 * C2 * 4);
  float* pooled = (float*)alloc(2 * C2 * 4);
  float* bias1  = (float*)alloc(4 * C1 * 4);
  float* bias2  = (float*)alloc(4 * C2 * 4);
  half2_t* Wp1  = (half2_t*)alloc((size_t)(C1 / 2) * 4 * C1 * 4);
  half2_t* Wp2  = (half2_t*)alloc((size_t)(C2 / 2) * 4 * C2 * 4);
  bf16_t* Wih1b = (bf16_t*)alloc((size_t)4 * C1 * IN1P * 2);
  bf16_t* Wih2b = (bf16_t*)alloc((size_t)4 * C2 * IN2P * 2);
  bf16_t* W2b   = (bf16_t*)alloc((size_t)C2 * KG2P * 2);
  unsigned short* lut1 = (unsigned short*)alloc((size_t)P1 * 2);
  unsigned short* lut2 = (unsigned short*)alloc((size_t)P2 * 2);
  size_t pmax = (size_t)Z2 * 3000 * 768;
  {
    size_t p1s = (size_t)Z1 * 5000 * 384; if (p1s > pmax) pmax = p1s;
    size_t pgs = (size_t)ZG * 5000 * 192; if (pgs > pmax) pmax = pgs;
  }
  float* Pbuf = (float*)alloc(pmax * 4);
  bf16_t* feats = (bf16_t*)alloc((size_t)B * S2 * IN2P * 2);
  (void)ws_size; (void)in_sizes; (void)n_in; (void)out_size;

  // 1) prep: adds, whh packs, LUTs, stat zeros, A2mat K-pad
  prep_misc<<<625, 256, 0, stream>>>(A_powers1, A_res1, A1full, A_powers2, A_res2, A2full,
                                     bih1, bhh1, bias1, bih2, bhh2, bias2,
                                     Whh1, Wp1, Whh2, Wp2, lut1, lut2, stats, A2mat);
  // 2) weight bf16 conversion (one dispatch)
  {
    int c1 = 4 * C1 * (IN1P / 8);
    int c2 = 4 * C2 * (IN2P / 8);
    int c3 = C2 * (KG2P / 8);
    int tot = c1 + c2 + c3;
    f2bf_pad8_3<<<(tot + 255) / 256, 256, 0, stream>>>(Wih1, Wih1b, IN1, IN1P, c1,
                                                       Wih2, Wih2b, IN2, IN2P, c2,
                                                       W2, W2b, KG2, KG2P, c3);
  }

  // 3) data BN
  data_bn_kernel<<<M * V * C, 64, 0, stream>>>(x, data_bn_g, data_bn_b, h1, N, C, T, V, M);

  // 4) GCN1 fused (support + contract + stats)
  gcn1_fused<<<NM * T, 256, 0, stream>>>(A1full, h1, W1, b1, y1mat, st1a, st1b, T);

  SegTable seg1, seg2; int L1, L2;
  make_segs(T, S1, seg1, L1);
  make_segs(S1, S2, seg2, L2);

  // 5) feats1 (bn+relu inline)
  feats_bn_kernel<<<B * S1, 256, 0, stream>>>(y1mat, st1a, st1b, bn1_g, bn1_b, feats, seg1,
                                              (const unsigned int*)lut1, T, C1, S1, L1, P1, IN1P,
                                              NM * T * 25);
  // 6) xp1 GEMM + 7) lstm1 (+segstats fused)
  {
    int Mm = B * S1, Nn = 4 * C1;
    dim3 g((Mm + 127) / 128, (Nn + 127) / 128, Z1);
    gemm_mfma_nt_split<<<g, 256, 0, stream>>>(feats, Wih1b, Pbuf, Mm, Nn, IN1P);
    lstm_kernel<48, 384, Z1><<<B, 384, 0, stream>>>(Pbuf, bias1, Wp1, l1out, sg1a, sg1b, S1, Mm * Nn);
  }

  // 8) support2 (+bnseg inline)
  {
    int tot = NM * S1 * 25 * 13 * 96;
    support2_bn<<<(tot + 255) / 256, 256, 0, stream>>>(A2full, l1out, sg1a, sg1b, bnseg1_g,
                                                       bnseg1_b, A2mat, S1, B * C1);
  }
  // 9) GCN2 GEMM + 10) reduce+bias+colstats
  {
    int Mm = NM * S1 * 25, Nn = C2;
    dim3 g((Mm + 127) / 128, (Nn + 127) / 128, ZG);
    gemm_mfma_nt_split<<<g, 256, 0, stream>>>(A2mat, W2b, Pbuf, Mm, Nn, KG2P);
    int MN = Mm * Nn;
    reduce_split_bias_stats<<<(MN / 4 + 255) / 256, 256, 0, stream>>>(Pbuf, b2, y2mat, st2a, st2b,
                                                                      MN, Nn, ZG);
  }

  // 11) feats2 (bn+relu inline)
  feats_bn_kernel<<<B * S2, 256, 0, stream>>>(y2mat, st2a, st2b, bn2_g, bn2_b, feats, seg2,
                                              (const unsigned int*)lut2, S1, C2, S2, L2, P2, IN2P,
                                              NM * S1 * 25);
  // 12) xp2 GEMM + 13) lstm2 (+segstats fused)
  {
    int Mm = B * S2, Nn = 4 * C2;
    dim3 g((Mm + 127) / 128, (Nn + 127) / 128, Z2);
    gemm_mfma_nt_split<<<g, 256, 0, stream>>>(feats, Wih2b, Pbuf, Mm, Nn, IN2P);
    lstm_kernel<96, 768, Z2><<<B, 768, 0, stream>>>(Pbuf, bias2, Wp2, l2out, sg2a, sg2b, S2, Mm * Nn);
  }

  // 14) pool, 15) fc
  pool_kernel<<<2 * C2, 64, 0, stream>>>(l2out, sg2a, sg2b, bnseg2_g, bnseg2_b, pooled, S2, C2, B * C2);
  fc_kernel<<<1, 128, 0, stream>>>(pooled, fcW, fcb, out);
}